// Round 8
// baseline (296.130 us; speedup 1.0000x reference)
//
#include <hip/hip_runtime.h>
#include <hip/hip_fp16.h>
#include <stdint.h>

// ---------------------------------------------------------------------------
// GCN 3-layer forward, MI355X. Round 8:
//  - k_mfma: one block per 64-row A panel (grid 782x1), A staged ONCE whole-K;
//    inner loop over (col-tile, k-tile) re-stages only the 32KB B tile, with
//    B-frag reg preload -> barrier -> issue-next-stage -> MFMA+epilogue
//    (threefry overlaps B staging). Kills the 4x/2x A panel re-reads.
//  - precision: split-f16 (hi + lo*2048, dual acc, combine accH+accL/2048).
//    h1 stored as SINGLE f16 (halves the biggest tensor; GEMM-2 = 2 MFMA).
// Pipeline:
//   CSR; xs16=f16(x*dinv); ag=dt*sum xs16 (f16 hi/lo'); h1=relu(drop(ag@W1+b1)) f16;
//   hw2=f16((h1@W2)*dinv); h2=relu(drop(dt*sum hw2+b2)) (f16 hi/lo'); out=h2@W3+b3.
// ---------------------------------------------------------------------------

typedef __attribute__((ext_vector_type(8))) short s8v;   // 8 f16 (4 VGPR)
typedef __attribute__((ext_vector_type(4))) float f4v;   // 4 f32 acc

__device__ __host__ __forceinline__ uint32_t tf_rotl(uint32_t v, int r) {
  return (v << r) | (v >> (32 - r));
}

__device__ __host__ __forceinline__ void threefry2x32(uint32_t k0, uint32_t k1,
                                                      uint32_t x0, uint32_t x1,
                                                      uint32_t& o0, uint32_t& o1) {
  const uint32_t k2 = k0 ^ k1 ^ 0x1BD11BDAu;
  x0 += k0; x1 += k1;
#define TFR(r) { x0 += x1; x1 = tf_rotl(x1, r); x1 ^= x0; }
  TFR(13) TFR(15) TFR(26) TFR(6)
  x0 += k1; x1 += k2 + 1u;
  TFR(17) TFR(29) TFR(16) TFR(24)
  x0 += k2; x1 += k0 + 2u;
  TFR(13) TFR(15) TFR(26) TFR(6)
  x0 += k0; x1 += k1 + 3u;
  TFR(17) TFR(29) TFR(16) TFR(24)
  x0 += k1; x1 += k2 + 4u;
  TFR(13) TFR(15) TFR(26) TFR(6)
  x0 += k2; x1 += k0 + 5u;
#undef TFR
  o0 = x0; o1 = x1;
}

__device__ __forceinline__ bool drop_keep(uint32_t k0, uint32_t k1, uint32_t j) {
  uint32_t a, b;
  threefry2x32(k0, k1, 0u, j, a, b);
  uint32_t bits = a ^ b;
  float u = __uint_as_float((bits >> 9) | 0x3f800000u) - 1.0f;
  return u < 0.8f;
}

// f16 hi / scaled-lo helpers (lo pre-scaled by 2048 to stay in normal range)
__device__ __forceinline__ void split16(float v, uint16_t& h, uint16_t& l) {
  __half hh = __float2half_rn(v);
  h = __half_as_ushort(hh);
  l = __half_as_ushort(__float2half_rn((v - __half2float(hh)) * 2048.0f));
}

// async global->LDS, 16B/lane; lds base wave-uniform (HW adds lane*16)
__device__ __forceinline__ void gll16(const void* g, void* l) {
  __builtin_amdgcn_global_load_lds(
      (const __attribute__((address_space(1))) uint32_t*)g,
      (__attribute__((address_space(3))) uint32_t*)l, 16, 0, 0);
}

// ------------------------- CSR build -------------------------
__global__ void k_hist(const int* __restrict__ tgt, int* __restrict__ cnt, int E) {
  int e = blockIdx.x * 256 + threadIdx.x;
  if (e < E) atomicAdd(&cnt[tgt[e]], 1);
}

__global__ __launch_bounds__(256) void k_scan1(const int* __restrict__ cnt,
                                               int* __restrict__ row_start,
                                               int* __restrict__ bsum,
                                               float* __restrict__ dinv, int n) {
  int tid = threadIdx.x;
  int i = blockIdx.x * 256 + tid;
  int c = (i < n) ? cnt[i] : 0;
  if (i < n) dinv[i] = rsqrtf((float)(c + 1));  // +1 self-loop
  int lane = tid & 63, wv = tid >> 6;
  int v = c;
#pragma unroll
  for (int d = 1; d < 64; d <<= 1) {
    int u = __shfl_up(v, d);
    if (lane >= d) v += u;
  }
  __shared__ int ws[4];
  if (lane == 63) ws[wv] = v;
  __syncthreads();
  int add = 0;
#pragma unroll
  for (int w = 0; w < 4; ++w)
    if (w < wv) add += ws[w];
  int incl = v + add;
  if (i < n) row_start[i] = incl - c;
  if (tid == 255) bsum[blockIdx.x] = incl;
}

__global__ __launch_bounds__(256) void k_scan2(const int* __restrict__ bsum,
                                               int* __restrict__ bbase,
                                               int* __restrict__ row_start,
                                               int nb, int n) {
  int tid = threadIdx.x;
  int c = (tid < nb) ? bsum[tid] : 0;
  int lane = tid & 63, wv = tid >> 6;
  int v = c;
#pragma unroll
  for (int d = 1; d < 64; d <<= 1) {
    int u = __shfl_up(v, d);
    if (lane >= d) v += u;
  }
  __shared__ int ws[4];
  if (lane == 63) ws[wv] = v;
  __syncthreads();
  int add = 0;
#pragma unroll
  for (int w = 0; w < 4; ++w)
    if (w < wv) add += ws[w];
  int incl = v + add;
  if (tid < nb) bbase[tid] = incl - c;
  if (tid == 255) row_start[n] = incl;
}

__global__ void k_scan3(int* __restrict__ row_start, const int* __restrict__ bbase, int n) {
  int i = blockIdx.x * 256 + threadIdx.x;
  if (i < n) row_start[i] += bbase[blockIdx.x];
}

__global__ void k_scatter(const int* __restrict__ src, const int* __restrict__ tgt,
                          const int* __restrict__ row_start, int* __restrict__ cursor,
                          int* __restrict__ csr_src, int E) {
  int e = blockIdx.x * 256 + threadIdx.x;
  if (e >= E) return;
  int t = tgt[e];
  int pos = atomicAdd(&cursor[t], 1);
  csr_src[row_start[t] + pos] = src[e];
}

// ------------------------- weight transpose + f16 hi/lo' split ----------------------
__global__ void k_cvtW(const float* __restrict__ W, uint16_t* __restrict__ Wth,
                       uint16_t* __restrict__ Wtl, int K, int N) {
  int i = blockIdx.x * 256 + threadIdx.x;
  if (i >= N * K) return;
  int nn = i / K, kk = i - nn * K;
  float v = W[(size_t)kk * N + nn];
  split16(v, Wth[i], Wtl[i]);
}

// ------------------------- xs16 = f16(x * dinv[row]) -------------------------
__global__ void k_scale16(const float* __restrict__ x, const float* __restrict__ dinv,
                          uint16_t* __restrict__ xs, int total2) {
  int i = blockIdx.x * 256 + threadIdx.x;
  if (i >= total2) return;
  float2 v = ((const float2*)x)[i];
  float s = dinv[i >> 6];
  __half2 h;
  h.x = __float2half_rn(v.x * s);
  h.y = __float2half_rn(v.y * s);
  ((__half2*)xs)[i] = h;
}

// ------------------------- split-f16 MFMA GEMM, A staged once --------------------
// Block = 64 A-rows x full N. A panel (whole K) in LDS once; B tiles (64 cols x
// 128 K, hi+lo') re-staged per (ct,kt) with reg-preload + overlap.
// ASPLIT: A has hi + scaled-lo arrays (K=128). !ASPLIT: A single f16, K=256, NKT=2.
// MODE 0: C16 = f16(v*sb[row]);  MODE 1: Cf = v+sb[col];  MODE 2: C16 = f16(relu(drop(v+sb[col])))
template <int NCT, bool ASPLIT, int MODE>
__global__ __launch_bounds__(256) void k_mfma(
    const uint16_t* __restrict__ Ah, const uint16_t* __restrict__ Al,
    const uint16_t* __restrict__ Bh, const uint16_t* __restrict__ Bl,
    const float* __restrict__ sb, float* __restrict__ Cf,
    uint16_t* __restrict__ C16,
    int M, uint32_t k0, uint32_t k1) {
  constexpr int K = ASPLIT ? 128 : 256;
  constexpr int NKT = ASPLIT ? 1 : 2;
  constexpr int N = NCT * 64;
  extern __shared__ uint16_t smem[];
  uint16_t* lA = smem;            // 16384 elems: [2][64][128] or [64][256]
  uint16_t* lB = smem + 16384;    // 16384 elems: [2][64][128]

  int tid = threadIdx.x;
  int lane = tid & 63;
  int wid = tid >> 6;
  int r16 = lane & 15, kq = lane >> 4;
  int bm = blockIdx.x * 64;

  // ---- stage A panel (whole K) once ----
#pragma unroll
  for (int p = 0; p < 8; ++p) {
    int c = p * 256 + tid;
    int cbase = p * 256 + (wid << 6);
    if (ASPLIT) {
      int arr = c >> 10, cc = c & 1023;
      int row = cc >> 4, seg = (cc & 15) ^ (row & 7);
      const uint16_t* src = (arr ? Al : Ah) + (size_t)(bm + row) * K + seg * 8;
      gll16(src, lA + (size_t)cbase * 8);
    } else {
      int row = c >> 5, seg = (c & 31) ^ (row & 7);
      gll16(Ah + (size_t)(bm + row) * K + seg * 8, lA + (size_t)cbase * 8);
    }
  }

  auto stageB = [&](int ct, int kt) {
#pragma unroll
    for (int p = 0; p < 8; ++p) {
      int c = p * 256 + tid;
      int cbase = p * 256 + (wid << 6);
      int arr = c >> 10, cc = c & 1023;
      int row = cc >> 4, seg = (cc & 15) ^ (row & 7);
      const uint16_t* src = (arr ? Bl : Bh) + (size_t)(ct * 64 + row) * K + kt * 128 + seg * 8;
      gll16(src, lB + (size_t)cbase * 8);
    }
  };
  stageB(0, 0);
  asm volatile("s_waitcnt vmcnt(0)" ::: "memory");
  __syncthreads();

  int iter = 0;
  for (int ct = 0; ct < NCT; ++ct) {
    f4v accH[4] = {};
    f4v accL[4] = {};
    for (int kt = 0; kt < NKT; ++kt, ++iter) {
      // ---- preload B frags to regs ----
      s8v bh[4], bl[4];
      int brow = wid * 16 + r16;
      int bswz = brow & 7;
#pragma unroll
      for (int ks = 0; ks < 4; ++ks) {
        int sp = (ks * 4 + kq) ^ bswz;
        bh[ks] = *(const s8v*)&lB[brow * 128 + sp * 8];
        bl[ks] = *(const s8v*)&lB[8192 + brow * 128 + sp * 8];
      }
      __syncthreads();  // all waves done reading lB
      // ---- issue next B stage (hidden under compute + epilogue) ----
      if (iter + 1 < NCT * NKT) {
        int ni = iter + 1;
        stageB(ni / NKT, ni % NKT);
      }
      // ---- MFMA ----
#pragma unroll
      for (int ks = 0; ks < 4; ++ks) {
#pragma unroll
        for (int mb = 0; mb < 4; ++mb) {
          int row = mb * 16 + r16;
          int sp = (kt * 16 + ks * 4 + kq) ^ (row & 7);
          s8v a = *(const s8v*)&lA[row * K + sp * 8];
          accH[mb] = __builtin_amdgcn_mfma_f32_16x16x32_f16(a, bh[ks], accH[mb], 0, 0, 0);
          if (ASPLIT) {
            s8v al = *(const s8v*)&lA[8192 + row * 128 + sp * 8];
            accL[mb] = __builtin_amdgcn_mfma_f32_16x16x32_f16(a, bl[ks], accL[mb], 0, 0, 0);
            accL[mb] = __builtin_amdgcn_mfma_f32_16x16x32_f16(al, bh[ks], accL[mb], 0, 0, 0);
          } else {
            accL[mb] = __builtin_amdgcn_mfma_f32_16x16x32_f16(a, bl[ks], accL[mb], 0, 0, 0);
          }
        }
      }
      // ---- epilogue for this col-tile (overlaps B staging) ----
      if (kt == NKT - 1) {
#pragma unroll
        for (int mb = 0; mb < 4; ++mb) {
#pragma unroll
          for (int r = 0; r < 4; ++r) {
            int row = bm + mb * 16 + kq * 4 + r;
            int col = ct * 64 + wid * 16 + r16;
            if (row < M) {
              float v = accH[mb][r] + accL[mb][r] * (1.0f / 2048.0f);
              size_t o = (size_t)row * N + col;
              if (MODE == 0) {
                C16[o] = __half_as_ushort(__float2half_rn(v * sb[row]));
              } else if (MODE == 1) {
                Cf[o] = v + sb[col];
              } else {
                v += sb[col];
                uint32_t j = (uint32_t)row * (uint32_t)N + (uint32_t)col;
                v = drop_keep(k0, k1, j) ? fmaxf(v * 1.25f, 0.f) : 0.f;
                C16[o] = __half_as_ushort(__float2half_rn(v));
              }
            }
          }
        }
      }
      asm volatile("s_waitcnt vmcnt(0)" ::: "memory");
      __syncthreads();
    }
  }
}

// ------------------------- layer-1 aggregation (f16 gather, MLP-8) ----------------
__global__ __launch_bounds__(256) void k_agg_x(const uint16_t* __restrict__ xs,
                                               const float* __restrict__ dinv,
                                               const int* __restrict__ row_start,
                                               const int* __restrict__ csr_src,
                                               uint32_t* __restrict__ outh,
                                               uint32_t* __restrict__ outl, int n) {
  const int F = 128;
  int wid = (int)((blockIdx.x * 256 + threadIdx.x) >> 6);
  if (wid >= n) return;
  int lane = threadIdx.x & 63;
  int t = wid;
  float2 a[8];
  a[0] = __half22float2(((const __half2*)(xs + (size_t)t * F))[lane]);
#pragma unroll
  for (int q = 1; q < 8; ++q) a[q] = make_float2(0.f, 0.f);
  int e0 = row_start[t], e1 = row_start[t + 1];
  int e = e0;
  for (; e + 8 <= e1; e += 8) {
#pragma unroll
    for (int q = 0; q < 8; ++q) {
      int s = csr_src[e + q];
      float2 v = __half22float2(((const __half2*)(xs + (size_t)s * F))[lane]);
      a[q].x += v.x;
      a[q].y += v.y;
    }
  }
  for (; e < e1; ++e) {
    int s = csr_src[e];
    float2 v = __half22float2(((const __half2*)(xs + (size_t)s * F))[lane]);
    a[0].x += v.x; a[0].y += v.y;
  }
  float dt = dinv[t];
  float rx = (((a[0].x + a[1].x) + (a[2].x + a[3].x)) + ((a[4].x + a[5].x) + (a[6].x + a[7].x))) * dt;
  float ry = (((a[0].y + a[1].y) + (a[2].y + a[3].y)) + ((a[4].y + a[5].y) + (a[6].y + a[7].y))) * dt;
  uint16_t hx, lx, hy, ly;
  split16(rx, hx, lx);
  split16(ry, hy, ly);
  outh[(size_t)t * 64 + lane] = (uint32_t)hx | ((uint32_t)hy << 16);
  outl[(size_t)t * 64 + lane] = (uint32_t)lx | ((uint32_t)ly << 16);
}

// ------------------------- layer-2 aggregation + bias + drop + relu ---------------
__global__ __launch_bounds__(256) void k_agg_w(const uint16_t* __restrict__ hws,
                                               const float* __restrict__ dinv,
                                               const float* __restrict__ bias,
                                               const int* __restrict__ row_start,
                                               const int* __restrict__ csr_src,
                                               uint32_t* __restrict__ outh,
                                               uint32_t* __restrict__ outl,
                                               uint32_t k0, uint32_t k1, int n) {
  const int F = 128;
  int wid = (int)((blockIdx.x * 256 + threadIdx.x) >> 6);
  if (wid >= n) return;
  int lane = threadIdx.x & 63;
  int t = wid;
  float2 a[8];
  a[0] = __half22float2(((const __half2*)(hws + (size_t)t * F))[lane]);
#pragma unroll
  for (int q = 1; q < 8; ++q) a[q] = make_float2(0.f, 0.f);
  int e0 = row_start[t], e1 = row_start[t + 1];
  int e = e0;
  for (; e + 8 <= e1; e += 8) {
#pragma unroll
    for (int q = 0; q < 8; ++q) {
      int s = csr_src[e + q];
      float2 v = __half22float2(((const __half2*)(hws + (size_t)s * F))[lane]);
      a[q].x += v.x;
      a[q].y += v.y;
    }
  }
  for (; e < e1; ++e) {
    int s = csr_src[e];
    float2 v = __half22float2(((const __half2*)(hws + (size_t)s * F))[lane]);
    a[0].x += v.x; a[0].y += v.y;
  }
  float d = dinv[t];
  float sx = ((a[0].x + a[1].x) + (a[2].x + a[3].x)) + ((a[4].x + a[5].x) + (a[6].x + a[7].x));
  float sy = ((a[0].y + a[1].y) + (a[2].y + a[3].y)) + ((a[4].y + a[5].y) + (a[6].y + a[7].y));
  float vx = sx * d + bias[lane * 2];
  float vy = sy * d + bias[lane * 2 + 1];
  uint32_t j = (uint32_t)t * 128u + (uint32_t)lane * 2u;
  vx = drop_keep(k0, k1, j)     ? fmaxf(vx * 1.25f, 0.f) : 0.f;
  vy = drop_keep(k0, k1, j + 1) ? fmaxf(vy * 1.25f, 0.f) : 0.f;
  uint16_t hx, lx, hy, ly;
  split16(vx, hx, lx);
  split16(vy, hy, ly);
  outh[(size_t)t * 64 + lane] = (uint32_t)hx | ((uint32_t)hy << 16);
  outl[(size_t)t * 64 + lane] = (uint32_t)lx | ((uint32_t)ly << 16);
}

// ------------------------- launch -------------------------
static inline size_t ws_align(size_t x) { return (x + 255) & ~(size_t)255; }

extern "C" void kernel_launch(void* const* d_in, const int* in_sizes, int n_in,
                              void* d_out, int out_size, void* d_ws, size_t ws_size,
                              hipStream_t stream) {
  const float* x  = (const float*)d_in[0];
  const float* W1 = (const float*)d_in[1];
  const float* b1 = (const float*)d_in[2];
  const float* W2 = (const float*)d_in[3];
  const float* b2 = (const float*)d_in[4];
  const float* W3 = (const float*)d_in[5];
  const float* b3 = (const float*)d_in[6];
  const int*   ei = (const int*)d_in[7];

  const int IN = 128, H2 = 256, HID = 128, OD = 64;
  const int n = in_sizes[0] / IN;   // 50000
  const int E = in_sizes[7] / 2;    // 800000
  const int* esrc = ei;
  const int* etgt = ei + E;
  const int nb = (n + 255) / 256;
  const int Mb64 = (n + 63) / 64;   // 782
  const int Mpad = Mb64 * 64;       // 50048

  char* w = (char*)d_ws;
  size_t off = 0;
  auto alloc = [&](size_t bytes) { void* p = w + off; off += ws_align(bytes); return p; };
  float*    dinv      = (float*)alloc((size_t)n * 4);
  int*      cnt       = (int*)alloc((size_t)n * 4);
  int*      cursor    = (int*)alloc((size_t)n * 4);
  int*      row_start = (int*)alloc(((size_t)n + 1) * 4);
  int*      bsum      = (int*)alloc(256 * 4);
  int*      bbase     = (int*)alloc(256 * 4);
  int*      csr_src   = (int*)alloc((size_t)E * 4);
  uint16_t* xs16      = (uint16_t*)alloc((size_t)n * IN * 2);
  uint16_t* A1h       = (uint16_t*)alloc((size_t)Mpad * IN * 2);   // ag / h2 hi (aliased)
  uint16_t* A1l       = (uint16_t*)alloc((size_t)Mpad * IN * 2);   // ag / h2 lo'
  uint16_t* h1_16     = (uint16_t*)alloc((size_t)Mpad * H2 * 2);   // h1 single f16
  uint16_t* hw2_16    = (uint16_t*)alloc((size_t)n * HID * 2);
  uint16_t* Wt1h      = (uint16_t*)alloc((size_t)H2 * IN * 2);
  uint16_t* Wt1l      = (uint16_t*)alloc((size_t)H2 * IN * 2);
  uint16_t* Wt2h      = (uint16_t*)alloc((size_t)HID * H2 * 2);
  uint16_t* Wt2l      = (uint16_t*)alloc((size_t)HID * H2 * 2);
  uint16_t* Wt3h      = (uint16_t*)alloc((size_t)OD * IN * 2);
  uint16_t* Wt3l      = (uint16_t*)alloc((size_t)OD * IN * 2);
  (void)ws_size;

  hipFuncSetAttribute((const void*)&k_mfma<4, true, 2>,
                      hipFuncAttributeMaxDynamicSharedMemorySize, 65536);
  hipFuncSetAttribute((const void*)&k_mfma<2, false, 0>,
                      hipFuncAttributeMaxDynamicSharedMemorySize, 65536);
  hipFuncSetAttribute((const void*)&k_mfma<1, true, 1>,
                      hipFuncAttributeMaxDynamicSharedMemorySize, 65536);

  uint32_t dk1_0, dk1_1, dk2_0, dk2_1;
  threefry2x32(0u, 42u, 0u, 0u, dk1_0, dk1_1);
  threefry2x32(0u, 42u, 0u, 1u, dk2_0, dk2_1);

  int padrows = Mpad - n;  // 48
  hipMemsetAsync(A1h + (size_t)n * IN, 0, (size_t)padrows * IN * 2, stream);
  hipMemsetAsync(A1l + (size_t)n * IN, 0, (size_t)padrows * IN * 2, stream);
  hipMemsetAsync(h1_16 + (size_t)n * H2, 0, (size_t)padrows * H2 * 2, stream);
  hipMemsetAsync(cnt, 0, (size_t)n * 4, stream);
  hipMemsetAsync(cursor, 0, (size_t)n * 4, stream);

  k_cvtW<<<(H2 * IN + 255) / 256, 256, 0, stream>>>(W1, Wt1h, Wt1l, IN, H2);
  k_cvtW<<<(HID * H2 + 255) / 256, 256, 0, stream>>>(W2, Wt2h, Wt2l, H2, HID);
  k_cvtW<<<(OD * IN + 255) / 256, 256, 0, stream>>>(W3, Wt3h, Wt3l, IN, OD);

  k_hist<<<(E + 255) / 256, 256, 0, stream>>>(etgt, cnt, E);
  k_scan1<<<nb, 256, 0, stream>>>(cnt, row_start, bsum, dinv, n);
  k_scan2<<<1, 256, 0, stream>>>(bsum, bbase, row_start, nb, n);
  k_scan3<<<nb, 256, 0, stream>>>(row_start, bbase, n);
  k_scatter<<<(E + 255) / 256, 256, 0, stream>>>(esrc, etgt, row_start, cursor, csr_src, E);

  // layer 1
  int total2 = n * IN / 2;
  k_scale16<<<(total2 + 255) / 256, 256, 0, stream>>>(x, dinv, xs16, total2);
  k_agg_x<<<(n + 3) / 4, 256, 0, stream>>>(xs16, dinv, row_start, csr_src,
                                           (uint32_t*)A1h, (uint32_t*)A1l, n);
  k_mfma<4, true, 2><<<Mb64, 256, 65536, stream>>>(A1h, A1l, Wt1h, Wt1l, b1, nullptr,
                                                   h1_16, n, dk1_0, dk1_1);

  // layer 2
  k_mfma<2, false, 0><<<Mb64, 256, 65536, stream>>>(h1_16, nullptr, Wt2h, Wt2l, dinv,
                                                    nullptr, hw2_16, n, 0u, 0u);
  k_agg_w<<<(n + 3) / 4, 256, 0, stream>>>(hw2_16, dinv, b2, row_start, csr_src,
                                           (uint32_t*)A1h, (uint32_t*)A1l, dk2_0, dk2_1, n);

  // layer 3
  k_mfma<1, true, 1><<<Mb64, 256, 65536, stream>>>(A1h, A1l, Wt3h, Wt3l, b3,
                                                   (float*)d_out, nullptr, n, 0u, 0u);
}